// Round 5
// baseline (295.300 us; speedup 1.0000x reference)
//
#include <hip/hip_runtime.h>
#include <hip/hip_bf16.h>

typedef unsigned short u16;
typedef unsigned int   uint;
typedef __attribute__((ext_vector_type(8))) short bf16x8;
typedef __attribute__((ext_vector_type(4))) float f32x4;

constexpr int NELEM = 100;
constexpr int EMBED = 256;
constexpr int HID   = 512;
constexpr int KX    = 306;     // EMBED + 50
constexpr int G     = 50;
constexpr int M     = 64;      // edges (or pair-rows) per block
constexpr int THREADS = 512;   // 8 waves

// d_ws layout (bytes):
//  Wb [32nt][10ks][64][8] bf16 | Gb [32nt][2ks][64][8] | Ob [16][64][8]
//  hpreF [NPAIR][512] f32  (= emb_table @ W_emb.T via MFMA ks 0..7)
//  mode A: tmp [E][8] f32 | ip [E] i32 (iperm) | pairids [E] u16 | spair [E] u16
//          | sdist [E] f32 | bins [NPAIR] i32                  (38.6 MB)
//  mode B: ip=perm [E] i32 | pairids | spair | bins            (24.1 MB, = r3)
//  mode C: Wb..hpreF only (unsorted main)                      (20.9 MB)
constexpr int WB_ELEMS = 32 * 10 * 64 * 8;   // 163840
constexpr int GB_ELEMS = 32 * 2 * 64 * 8;    // 32768
constexpr int OB_ELEMS = 16 * 64 * 8;        // 8192
constexpr int WEIGHT_ELEMS = WB_ELEMS + GB_ELEMS + OB_ELEMS;   // 204800
constexpr int NPREP = WEIGHT_ELEMS / THREADS;                  // 400 (exact)

__device__ __forceinline__ u16 f2bf(float x) {
    uint u = __float_as_uint(x);
    u = (u + 0x7fffu + ((u >> 16) & 1u)) >> 16;
    return (u16)u;
}
__device__ __forceinline__ uint pk2(float a, float b) {
    __hip_bfloat162 h = __float22bfloat162_rn(make_float2(a, b));
    return *reinterpret_cast<uint*>(&h);
}
__device__ __forceinline__ float silu(float p) {
    return p * __builtin_amdgcn_rcpf(1.f + __expf(-p));
}
__device__ __forceinline__ f32x4 mfma16(bf16x8 a, bf16x8 b, f32x4 c) {
    return __builtin_amdgcn_mfma_f32_16x16x32_bf16(a, b, c, 0, 0, 0);
}

// ---- K1: weight frags (blocks < NPREP) + pair-id histogram (rest) ----------
__global__ __launch_bounds__(THREADS)
void prep_hist_kernel(const float* __restrict__ W_in,   // [512][306]
                      const float* __restrict__ gate_W, // [512][50]
                      const float* __restrict__ W_out,  // [8][512]
                      const float* __restrict__ b_in,   // [512]
                      const int* __restrict__ anum,
                      const int* __restrict__ edge_index,
                      const int* __restrict__ edge_to_src,
                      u16* __restrict__ Wb,
                      u16* __restrict__ Gb,
                      u16* __restrict__ Ob,
                      u16* __restrict__ pairids,
                      int* __restrict__ bins,
                      int E) {
    const int bid = blockIdx.x;
    const int t   = threadIdx.x;

    if (bid < NPREP) {                                  // ---- weight-frag part
        int idx = bid * THREADS + t;
        if (idx < WB_ELEMS) {
            int j = idx & 7, lane = (idx >> 3) & 63, kn = idx >> 9;
            int ks = kn % 10, nt = kn / 10;
            int h = nt * 16 + (lane & 15);
            int k = ks * 32 + (lane >> 4) * 8 + j;
            float v = (k < KX) ? W_in[h * KX + k] : ((k == KX) ? b_in[h] : 0.f);
            Wb[idx] = f2bf(v);
        } else if (idx < WB_ELEMS + GB_ELEMS) {
            int i2 = idx - WB_ELEMS;
            int j = i2 & 7, lane = (i2 >> 3) & 63, kn = i2 >> 9;
            int ks = kn & 1, nt = kn >> 1;
            int h = nt * 16 + (lane & 15);
            int g = ks * 32 + (lane >> 4) * 8 + j;
            Gb[i2] = f2bf((g < G) ? gate_W[h * G + g] : 0.f);
        } else {
            int i2 = idx - WB_ELEMS - GB_ELEMS;
            int j = i2 & 7, lane = (i2 >> 3) & 63, s = i2 >> 9;
            int m = lane & 15, q = lane >> 4;
            int hid = s * 32 + (j >> 2) * 16 + q * 4 + (j & 3);
            Ob[i2] = f2bf((m < 8) ? W_out[m * HID + hid] : 0.f);
        }
        return;
    }
    // ---- histogram part (only launched in sorted modes) --------------------
    int i = (bid - NPREP) * THREADS + t;
    if (i < E) {
        int src  = edge_to_src[i];
        int pair = anum[edge_index[src]] + NELEM * anum[edge_index[E + src]];
        pairids[i] = (u16)pair;
        atomicAdd(&bins[pair], 1);
    }
}

// ---- K2: exclusive scan of bins (in place: counts -> cursors) --------------
__global__ __launch_bounds__(THREADS)
void scan_kernel(int* __restrict__ bins, int npair) {
    __shared__ int lds[THREADS];
    const int t = threadIdx.x;
    const int chunk = (npair + THREADS - 1) / THREADS;
    const int lo = t * chunk;
    const int hi = min(lo + chunk, npair);
    int s = 0;
    for (int i = lo; i < hi; ++i) s += bins[i];
    lds[t] = s;
    __syncthreads();
    for (int off = 1; off < THREADS; off <<= 1) {
        int add = (t >= off) ? lds[t - off] : 0;
        __syncthreads();
        lds[t] += add;
        __syncthreads();
    }
    int excl = lds[t] - s;
    for (int i = lo; i < hi; ++i) {
        int c = bins[i];
        bins[i] = excl;
        excl += c;
    }
}

// ---- K3: scatter (blocks < nsc) + hpre GEMM from Wb frags (rest) -----------
__global__ __launch_bounds__(THREADS)
void scatter_hpre_kernel(const float* __restrict__ table,  // emb f32 [NPAIR][256]
                         const u16* __restrict__ Wb,
                         const u16* __restrict__ pairids,
                         const float* __restrict__ dist,
                         int* __restrict__ bins,           // cursors after scan
                         int* __restrict__ ip,             // iperm (A) / perm (B)
                         u16* __restrict__ spair,
                         float* __restrict__ sdist,        // mode A only
                         float* __restrict__ hpreF,
                         int E, int npair, int nsc, int mode_a) {
    __shared__ __align__(16) u16 af[8 * 4 * 64 * 8];   // 32 KB A-tile (hpre part)
    const int bid = blockIdx.x;
    const int t   = threadIdx.x;

    if (bid < nsc) {                                    // ---- scatter part
        int i = bid * THREADS + t;
        if (i < E) {
            int p   = pairids[i];
            int pos = atomicAdd(&bins[p], 1);
            if (mode_a) {
                ip[i]      = pos;        // inverse perm, coalesced write
                sdist[pos] = dist[i];
            } else {
                ip[pos] = i;             // forward perm
            }
            spair[pos] = (u16)p;
        }
        return;
    }

    // ---- hpre[p][h] = sum_{k<256} emb[p][k] * W_in[h][k] -------------------
    // Same MFMA sequence (ks 0..7, Wb frags) as the fused kernel; main's
    // acc-init + ks 8..9 continuation is bit-identical accumulation.
    const int pb = bid - nsc;
    const int p0 = pb * M;
    const int wave = t >> 6, lane = t & 63;
    const int col = lane & 15, quad = lane >> 4;

    #pragma unroll
    for (int mt = 0; mt < 4; ++mt) {
        int p = p0 + mt * 16 + col;
        uint4 w = {0u, 0u, 0u, 0u};
        if (p < npair) {
            const float* s = table + (size_t)p * EMBED + wave * 32 + quad * 8;
            float4 v0 = ((const float4*)s)[0], v1 = ((const float4*)s)[1];
            w.x = pk2(v0.x, v0.y); w.y = pk2(v0.z, v0.w);
            w.z = pk2(v1.x, v1.y); w.w = pk2(v1.z, v1.w);
        }
        *(uint4*)&af[((wave * 4 + mt) * 64 + lane) * 8] = w;
    }
    __syncthreads();

    const f32x4 z4 = {0.f, 0.f, 0.f, 0.f};
    #pragma unroll
    for (int nh = 0; nh < 2; ++nh) {
        f32x4 acc[2][4];
        #pragma unroll
        for (int ntl = 0; ntl < 2; ++ntl)
            #pragma unroll
            for (int mt = 0; mt < 4; ++mt) acc[ntl][mt] = z4;
        #pragma unroll 2
        for (int ks = 0; ks < 8; ++ks) {
            bf16x8 a[4];
            #pragma unroll
            for (int mt = 0; mt < 4; ++mt)
                a[mt] = *(const bf16x8*)&af[((ks * 4 + mt) * 64 + lane) * 8];
            #pragma unroll
            for (int ntl = 0; ntl < 2; ++ntl) {
                int ntg = wave * 4 + nh * 2 + ntl;
                bf16x8 wf = *(const bf16x8*)&Wb[((ntg * 10 + ks) * 64 + lane) * 8];
                #pragma unroll
                for (int mt = 0; mt < 4; ++mt)
                    acc[ntl][mt] = mfma16(wf, a[mt], acc[ntl][mt]);
            }
        }
        #pragma unroll
        for (int ntl = 0; ntl < 2; ++ntl)
            #pragma unroll
            for (int mt = 0; mt < 4; ++mt) {
                int p = p0 + mt * 16 + col;
                if (p < npair) {
                    int hb = (wave * 4 + nh * 2 + ntl) * 16 + quad * 4;
                    *(f32x4*)(hpreF + (size_t)p * HID + hb) = acc[ntl][mt];
                }
            }
    }
}

// ---- mode A main: sorted, coalesced reads + coalesced tmp writes -----------
__global__ __launch_bounds__(THREADS, 4)
void pair_embed_srtA(const u16* __restrict__ spair,
                     const float* __restrict__ sdist,
                     const float* __restrict__ hpreF,
                     const float* __restrict__ b_out,
                     const u16* __restrict__ Wb,
                     const u16* __restrict__ Gb,
                     const u16* __restrict__ Ob,
                     float* __restrict__ tmp,          // [E][8]
                     int E) {
    __shared__ __align__(16) u16 smem[16384];          // afrag 8KB | redf 32KB
    __shared__ int   rowbase[M];
    __shared__ float dste[M];
    u16*   afrag = smem;
    float* redf  = (float*)smem;

    const int t  = threadIdx.x;
    const int e0 = blockIdx.x * M;
    const int wave = t >> 6, lane = t & 63;
    const int col = lane & 15, quad = lane >> 4;

    if (t < M) {
        int slot = e0 + t;
        int pair = 0; float d = 0.f;
        if (slot < E) { pair = spair[slot]; d = sdist[slot]; }
        rowbase[t] = pair * HID;
        dste[t]    = d;
    }
    __syncthreads();

    int rbm[4];
    #pragma unroll
    for (int mt = 0; mt < 4; ++mt) rbm[mt] = rowbase[mt * 16 + col];

    f32x4 hp[2][4];
    #pragma unroll
    for (int mt = 0; mt < 4; ++mt) {
        const float* p = hpreF + rbm[mt] + (wave * 4) * 16 + quad * 4;
        hp[0][mt] = *(const f32x4*)p;
        hp[1][mt] = *(const f32x4*)(p + 16);
    }

    {   // rbf A-tile: wave w -> (ks = w&1, mt = w>>1)
        const float sp    = 12.0f / 49.0f;
        const float coeff = -0.5f / (sp * sp);
        int ks = wave & 1, mtr = wave >> 1;
        float d  = dste[mtr * 16 + col];
        int   g0 = ks * 32 + quad * 8;
        float f[8];
        #pragma unroll
        for (int j = 0; j < 8; ++j) {
            int g = g0 + j;
            float dd = d - sp * (float)g;
            f[j] = (g < G) ? __expf(coeff * dd * dd) : ((g == G) ? 1.f : 0.f);
        }
        uint4 w;
        w.x = pk2(f[0], f[1]); w.y = pk2(f[2], f[3]);
        w.z = pk2(f[4], f[5]); w.w = pk2(f[6], f[7]);
        *(uint4*)&afrag[((ks * 4 + mtr) * 64 + lane) * 8] = w;
    }
    __syncthreads();

    const f32x4 z4 = {0.f, 0.f, 0.f, 0.f};
    f32x4 oacc[4] = {z4, z4, z4, z4};

    #pragma unroll
    for (int nh = 0; nh < 2; ++nh) {
        if (nh == 1) {
            #pragma unroll
            for (int mt = 0; mt < 4; ++mt) {
                const float* p = hpreF + rbm[mt] + (wave * 4 + 2) * 16 + quad * 4;
                hp[0][mt] = *(const f32x4*)p;
                hp[1][mt] = *(const f32x4*)(p + 16);
            }
        }
        f32x4 acc[2][4], gacc[2][4];
        #pragma unroll
        for (int ntl = 0; ntl < 2; ++ntl)
            #pragma unroll
            for (int mt = 0; mt < 4; ++mt) {
                gacc[ntl][mt] = z4;
                acc[ntl][mt]  = hp[ntl][mt];
            }

        const u16* gb = &Gb[((wave * 4 + nh * 2) * 2 * 64 + lane) * 8];
        const u16* wb = &Wb[(((wave * 4 + nh * 2) * 10 + 8) * 64 + lane) * 8];
        #pragma unroll
        for (int ks = 0; ks < 2; ++ks) {
            bf16x8 a[4];
            #pragma unroll
            for (int mt = 0; mt < 4; ++mt)
                a[mt] = *(const bf16x8*)&afrag[((ks * 4 + mt) * 64 + lane) * 8];
            bf16x8 g0f = *(const bf16x8*)&gb[ks * 512];
            bf16x8 w0f = *(const bf16x8*)&wb[ks * 512];
            bf16x8 g1f = *(const bf16x8*)&gb[1024 + ks * 512];
            bf16x8 w1f = *(const bf16x8*)&wb[5120 + ks * 512];
            #pragma unroll
            for (int mt = 0; mt < 4; ++mt) gacc[0][mt] = mfma16(g0f, a[mt], gacc[0][mt]);
            #pragma unroll
            for (int mt = 0; mt < 4; ++mt) acc[0][mt]  = mfma16(w0f, a[mt], acc[0][mt]);
            #pragma unroll
            for (int mt = 0; mt < 4; ++mt) gacc[1][mt] = mfma16(g1f, a[mt], gacc[1][mt]);
            #pragma unroll
            for (int mt = 0; mt < 4; ++mt) acc[1][mt]  = mfma16(w1f, a[mt], acc[1][mt]);
        }

        bf16x8 obf = *(const bf16x8*)&Ob[(((wave << 1) | nh) * 64 + lane) * 8];
        #pragma unroll
        for (int mt = 0; mt < 4; ++mt) {
            uint4 hq;
            hq.x = pk2(silu(acc[0][mt][0]) * gacc[0][mt][0],
                       silu(acc[0][mt][1]) * gacc[0][mt][1]);
            hq.y = pk2(silu(acc[0][mt][2]) * gacc[0][mt][2],
                       silu(acc[0][mt][3]) * gacc[0][mt][3]);
            hq.z = pk2(silu(acc[1][mt][0]) * gacc[1][mt][0],
                       silu(acc[1][mt][1]) * gacc[1][mt][1]);
            hq.w = pk2(silu(acc[1][mt][2]) * gacc[1][mt][2],
                       silu(acc[1][mt][3]) * gacc[1][mt][3]);
            oacc[mt] = mfma16(obf, *(bf16x8*)&hq, oacc[mt]);
        }
    }
    __syncthreads();

    #pragma unroll
    for (int mt = 0; mt < 4; ++mt)
        *(f32x4*)&redf[((wave * 4 + mt) * 64 + lane) * 4] = oacc[mt];
    __syncthreads();

    {   // el = t>>3, head = t&7 => wave stores 256B contiguous to tmp
        int el = t >> 3, head = t & 7;
        int mt = el >> 4, c = el & 15;
        int l  = (head >> 2) * 16 + c;
        int r  = head & 3;
        float s = 0.f;
        #pragma unroll
        for (int w = 0; w < 8; ++w)
            s += redf[((w * 4 + mt) * 64 + l) * 4 + r];
        int slot = e0 + el;
        if (slot < E) tmp[slot * 8 + head] = s + b_out[head];
    }
}

// ---- permute: out[h][e] = tmp[ip[e]][h] (scattered reads, coalesced writes)
__global__ __launch_bounds__(256)
void permute_out_kernel(const int* __restrict__ iperm,
                        const float* __restrict__ tmp,
                        float* __restrict__ out, int E) {
    int e = blockIdx.x * 256 + threadIdx.x;
    if (e < E) {
        int s8 = iperm[e] * 8;
        f32x4 v0 = *(const f32x4*)(tmp + s8);
        f32x4 v1 = *(const f32x4*)(tmp + s8 + 4);
        #pragma unroll
        for (int h = 0; h < 4; ++h) out[h * E + e] = v0[h];
        #pragma unroll
        for (int h = 0; h < 4; ++h) out[(h + 4) * E + e] = v1[h];
    }
}

// ---- mode B main: sorted, direct scattered out-writes (round-3 proven) -----
__global__ __launch_bounds__(THREADS, 4)
void pair_embed_srtB(const int* __restrict__ perm,
                     const u16* __restrict__ spair,
                     const float* __restrict__ dist,
                     const float* __restrict__ hpreF,
                     const float* __restrict__ b_out,
                     const u16* __restrict__ Wb,
                     const u16* __restrict__ Gb,
                     const u16* __restrict__ Ob,
                     float* __restrict__ out,
                     int E) {
    __shared__ __align__(16) u16 smem[16384];
    __shared__ int   rowbase[M];
    __shared__ float dste[M];
    __shared__ int   oidx[M];
    u16*   afrag = smem;
    float* redf  = (float*)smem;

    const int t  = threadIdx.x;
    const int e0 = blockIdx.x * M;
    const int wave = t >> 6, lane = t & 63;
    const int col = lane & 15, quad = lane >> 4;

    if (t < M) {
        int slot = e0 + t;
        int pair = 0, orig = 0; float d = 0.f;
        if (slot < E) {
            orig = perm[slot];
            pair = spair[slot];
            d    = dist[orig];
        }
        rowbase[t] = pair * HID;
        dste[t]    = d;
        oidx[t]    = orig;
    }
    __syncthreads();

    int rbm[4];
    #pragma unroll
    for (int mt = 0; mt < 4; ++mt) rbm[mt] = rowbase[mt * 16 + col];

    f32x4 hp[2][4];
    #pragma unroll
    for (int mt = 0; mt < 4; ++mt) {
        const float* p = hpreF + rbm[mt] + (wave * 4) * 16 + quad * 4;
        hp[0][mt] = *(const f32x4*)p;
        hp[1][mt] = *(const f32x4*)(p + 16);
    }

    {
        const float sp    = 12.0f / 49.0f;
        const float coeff = -0.5f / (sp * sp);
        int ks = wave & 1, mtr = wave >> 1;
        float d  = dste[mtr * 16 + col];
        int   g0 = ks * 32 + quad * 8;
        float f[8];
        #pragma unroll
        for (int j = 0; j < 8; ++j) {
            int g = g0 + j;
            float dd = d - sp * (float)g;
            f[j] = (g < G) ? __expf(coeff * dd * dd) : ((g == G) ? 1.f : 0.f);
        }
        uint4 w;
        w.x = pk2(f[0], f[1]); w.y = pk2(f[2], f[3]);
        w.z = pk2(f[4], f[5]); w.w = pk2(f[6], f[7]);
        *(uint4*)&afrag[((ks * 4 + mtr) * 64 + lane) * 8] = w;
    }
    __syncthreads();

    const f32x4 z4 = {0.f, 0.f, 0.f, 0.f};
    f32x4 oacc[4] = {z4, z4, z4, z4};

    #pragma unroll
    for (int nh = 0; nh < 2; ++nh) {
        if (nh == 1) {
            #pragma unroll
            for (int mt = 0; mt < 4; ++mt) {
                const float* p = hpreF + rbm[mt] + (wave * 4 + 2) * 16 + quad * 4;
                hp[0][mt] = *(const f32x4*)p;
                hp[1][mt] = *(const f32x4*)(p + 16);
            }
        }
        f32x4 acc[2][4], gacc[2][4];
        #pragma unroll
        for (int ntl = 0; ntl < 2; ++ntl)
            #pragma unroll
            for (int mt = 0; mt < 4; ++mt) {
                gacc[ntl][mt] = z4;
                acc[ntl][mt]  = hp[ntl][mt];
            }

        const u16* gb = &Gb[((wave * 4 + nh * 2) * 2 * 64 + lane) * 8];
        const u16* wb = &Wb[(((wave * 4 + nh * 2) * 10 + 8) * 64 + lane) * 8];
        #pragma unroll
        for (int ks = 0; ks < 2; ++ks) {
            bf16x8 a[4];
            #pragma unroll
            for (int mt = 0; mt < 4; ++mt)
                a[mt] = *(const bf16x8*)&afrag[((ks * 4 + mt) * 64 + lane) * 8];
            bf16x8 g0f = *(const bf16x8*)&gb[ks * 512];
            bf16x8 w0f = *(const bf16x8*)&wb[ks * 512];
            bf16x8 g1f = *(const bf16x8*)&gb[1024 + ks * 512];
            bf16x8 w1f = *(const bf16x8*)&wb[5120 + ks * 512];
            #pragma unroll
            for (int mt = 0; mt < 4; ++mt) gacc[0][mt] = mfma16(g0f, a[mt], gacc[0][mt]);
            #pragma unroll
            for (int mt = 0; mt < 4; ++mt) acc[0][mt]  = mfma16(w0f, a[mt], acc[0][mt]);
            #pragma unroll
            for (int mt = 0; mt < 4; ++mt) gacc[1][mt] = mfma16(g1f, a[mt], gacc[1][mt]);
            #pragma unroll
            for (int mt = 0; mt < 4; ++mt) acc[1][mt]  = mfma16(w1f, a[mt], acc[1][mt]);
        }

        bf16x8 obf = *(const bf16x8*)&Ob[(((wave << 1) | nh) * 64 + lane) * 8];
        #pragma unroll
        for (int mt = 0; mt < 4; ++mt) {
            uint4 hq;
            hq.x = pk2(silu(acc[0][mt][0]) * gacc[0][mt][0],
                       silu(acc[0][mt][1]) * gacc[0][mt][1]);
            hq.y = pk2(silu(acc[0][mt][2]) * gacc[0][mt][2],
                       silu(acc[0][mt][3]) * gacc[0][mt][3]);
            hq.z = pk2(silu(acc[1][mt][0]) * gacc[1][mt][0],
                       silu(acc[1][mt][1]) * gacc[1][mt][1]);
            hq.w = pk2(silu(acc[1][mt][2]) * gacc[1][mt][2],
                       silu(acc[1][mt][3]) * gacc[1][mt][3]);
            oacc[mt] = mfma16(obf, *(bf16x8*)&hq, oacc[mt]);
        }
    }
    __syncthreads();

    #pragma unroll
    for (int mt = 0; mt < 4; ++mt)
        *(f32x4*)&redf[((wave * 4 + mt) * 64 + lane) * 4] = oacc[mt];
    __syncthreads();

    {
        int head = t >> 6, el = t & 63;
        int mt = el >> 4, c = el & 15;
        int l  = (head >> 2) * 16 + c;
        int r  = head & 3;
        float s = 0.f;
        #pragma unroll
        for (int w = 0; w < 8; ++w)
            s += redf[((w * 4 + mt) * 64 + l) * 4 + r];
        int slot = e0 + el;
        if (slot < E) out[head * E + oidx[el]] = s + b_out[head];
    }
}

// ---- mode C main: unsorted (round-2 proven path) ---------------------------
__global__ __launch_bounds__(THREADS, 4)
void pair_embed_unsrt(const int* __restrict__ anum,
                      const int* __restrict__ edge_index,
                      const int* __restrict__ edge_to_src,
                      const float* __restrict__ dist,
                      const float* __restrict__ hpreF,
                      const float* __restrict__ b_out,
                      const u16* __restrict__ Wb,
                      const u16* __restrict__ Gb,
                      const u16* __restrict__ Ob,
                      float* __restrict__ out,
                      int E) {
    __shared__ __align__(16) u16 smem[16384];
    __shared__ int   rowbase[M];
    __shared__ float dste[M];
    u16*   afrag = smem;
    float* redf  = (float*)smem;

    const int t  = threadIdx.x;
    const int e0 = blockIdx.x * M;
    const int wave = t >> 6, lane = t & 63;
    const int col = lane & 15, quad = lane >> 4;

    if (t < M) {
        int eg = e0 + t;
        int pair = 0; float d = 0.f;
        if (eg < E) {
            int src = edge_to_src[eg];
            pair = anum[edge_index[src]] + NELEM * anum[edge_index[E + src]];
            d = dist[eg];
        }
        rowbase[t] = pair * HID;
        dste[t]    = d;
    }
    __syncthreads();

    int rbm[4];
    #pragma unroll
    for (int mt = 0; mt < 4; ++mt) rbm[mt] = rowbase[mt * 16 + col];

    f32x4 hp[2][4];
    #pragma unroll
    for (int mt = 0; mt < 4; ++mt) {
        const float* p = hpreF + rbm[mt] + (wave * 4) * 16 + quad * 4;
        hp[0][mt] = *(const f32x4*)p;
        hp[1][mt] = *(const f32x4*)(p + 16);
    }

    {
        const float sp    = 12.0f / 49.0f;
        const float coeff = -0.5f / (sp * sp);
        int ks = wave & 1, mtr = wave >> 1;
        float d  = dste[mtr * 16 + col];
        int   g0 = ks * 32 + quad * 8;
        float f[8];
        #pragma unroll
        for (int j = 0; j < 8; ++j) {
            int g = g0 + j;
            float dd = d - sp * (float)g;
            f[j] = (g < G) ? __expf(coeff * dd * dd) : ((g == G) ? 1.f : 0.f);
        }
        uint4 w;
        w.x = pk2(f[0], f[1]); w.y = pk2(f[2], f[3]);
        w.z = pk2(f[4], f[5]); w.w = pk2(f[6], f[7]);
        *(uint4*)&afrag[((ks * 4 + mtr) * 64 + lane) * 8] = w;
    }
    __syncthreads();

    const f32x4 z4 = {0.f, 0.f, 0.f, 0.f};
    f32x4 oacc[4] = {z4, z4, z4, z4};

    #pragma unroll
    for (int nh = 0; nh < 2; ++nh) {
        if (nh == 1) {
            #pragma unroll
            for (int mt = 0; mt < 4; ++mt) {
                const float* p = hpreF + rbm[mt] + (wave * 4 + 2) * 16 + quad * 4;
                hp[0][mt] = *(const f32x4*)p;
                hp[1][mt] = *(const f32x4*)(p + 16);
            }
        }
        f32x4 acc[2][4], gacc[2][4];
        #pragma unroll
        for (int ntl = 0; ntl < 2; ++ntl)
            #pragma unroll
            for (int mt = 0; mt < 4; ++mt) {
                gacc[ntl][mt] = z4;
                acc[ntl][mt]  = hp[ntl][mt];
            }

        const u16* gb = &Gb[((wave * 4 + nh * 2) * 2 * 64 + lane) * 8];
        const u16* wb = &Wb[(((wave * 4 + nh * 2) * 10 + 8) * 64 + lane) * 8];
        #pragma unroll
        for (int ks = 0; ks < 2; ++ks) {
            bf16x8 a[4];
            #pragma unroll
            for (int mt = 0; mt < 4; ++mt)
                a[mt] = *(const bf16x8*)&afrag[((ks * 4 + mt) * 64 + lane) * 8];
            bf16x8 g0f = *(const bf16x8*)&gb[ks * 512];
            bf16x8 w0f = *(const bf16x8*)&wb[ks * 512];
            bf16x8 g1f = *(const bf16x8*)&gb[1024 + ks * 512];
            bf16x8 w1f = *(const bf16x8*)&wb[5120 + ks * 512];
            #pragma unroll
            for (int mt = 0; mt < 4; ++mt) gacc[0][mt] = mfma16(g0f, a[mt], gacc[0][mt]);
            #pragma unroll
            for (int mt = 0; mt < 4; ++mt) acc[0][mt]  = mfma16(w0f, a[mt], acc[0][mt]);
            #pragma unroll
            for (int mt = 0; mt < 4; ++mt) gacc[1][mt] = mfma16(g1f, a[mt], gacc[1][mt]);
            #pragma unroll
            for (int mt = 0; mt < 4; ++mt) acc[1][mt]  = mfma16(w1f, a[mt], acc[1][mt]);
        }

        bf16x8 obf = *(const bf16x8*)&Ob[(((wave << 1) | nh) * 64 + lane) * 8];
        #pragma unroll
        for (int mt = 0; mt < 4; ++mt) {
            uint4 hq;
            hq.x = pk2(silu(acc[0][mt][0]) * gacc[0][mt][0],
                       silu(acc[0][mt][1]) * gacc[0][mt][1]);
            hq.y = pk2(silu(acc[0][mt][2]) * gacc[0][mt][2],
                       silu(acc[0][mt][3]) * gacc[0][mt][3]);
            hq.z = pk2(silu(acc[1][mt][0]) * gacc[1][mt][0],
                       silu(acc[1][mt][1]) * gacc[1][mt][1]);
            hq.w = pk2(silu(acc[1][mt][2]) * gacc[1][mt][2],
                       silu(acc[1][mt][3]) * gacc[1][mt][3]);
            oacc[mt] = mfma16(obf, *(bf16x8*)&hq, oacc[mt]);
        }
    }
    __syncthreads();

    #pragma unroll
    for (int mt = 0; mt < 4; ++mt)
        *(f32x4*)&redf[((wave * 4 + mt) * 64 + lane) * 4] = oacc[mt];
    __syncthreads();

    {
        int head = t >> 6, el = t & 63;
        int mt = el >> 4, c = el & 15;
        int l  = (head >> 2) * 16 + c;
        int r  = head & 3;
        float s = 0.f;
        #pragma unroll
        for (int w = 0; w < 8; ++w)
            s += redf[((w * 4 + mt) * 64 + l) * 4 + r];
        int eg = e0 + el;
        if (eg < E) out[head * E + eg] = s + b_out[head];
    }
}

extern "C" void kernel_launch(void* const* d_in, const int* in_sizes, int n_in,
                              void* d_out, int out_size, void* d_ws, size_t ws_size,
                              hipStream_t stream) {
    const int*   anum        = (const int*)d_in[0];
    const int*   edge_index  = (const int*)d_in[1];
    const int*   edge_to_src = (const int*)d_in[2];
    const float* dist        = (const float*)d_in[3];
    const float* emb_table   = (const float*)d_in[4];
    const float* gate_W      = (const float*)d_in[5];
    const float* W_in        = (const float*)d_in[6];
    const float* b_in        = (const float*)d_in[7];
    const float* W_out       = (const float*)d_in[8];
    const float* b_out       = (const float*)d_in[9];
    const int E     = in_sizes[3];
    const int TBL   = in_sizes[4];
    const int NPAIR = TBL / EMBED;

    u16* Wb = (u16*)d_ws;
    u16* Gb = Wb + WB_ELEMS;
    u16* Ob = Gb + GB_ELEMS;
    const size_t WSW  = (size_t)WEIGHT_ELEMS * 2;           // 409600 B
    const size_t HB   = (size_t)NPAIR * HID * 4;            // f32 hpre
    const size_t TMPB = (size_t)E * 32;
    const size_t SRTA = (size_t)E * 12 + (size_t)NPAIR * 4; // ip+pairids+spair+sdist+bins
    const size_t SRTB = (size_t)E * 8  + (size_t)NPAIR * 4; // ip+pairids+spair+bins

    const size_t szA = WSW + HB + TMPB + SRTA;   // ~38.6 MB
    const size_t szB = WSW + HB + SRTB;          // ~24.1 MB (round-3 proven fit)
    const int mode = (ws_size >= szA) ? 2 : ((ws_size >= szB) ? 1 : 0);

    char*  hbase   = (char*)d_ws + WSW;
    float* hpreF   = (float*)hbase;
    float* tmp     = (float*)(hbase + HB);
    char*  q       = hbase + HB + ((mode == 2) ? TMPB : 0);
    int*   ip      = (int*)q;
    u16*   pairids = (u16*)(q + (size_t)E * 4);
    u16*   spair   = (u16*)(q + (size_t)E * 6);
    float* sdist   = (float*)(q + (size_t)E * 8);                       // A only
    int*   bins    = (int*)(q + (size_t)E * ((mode == 2) ? 12 : 8));

    const int nhist   = (E + THREADS - 1) / THREADS;
    const int npb     = (NPAIR + M - 1) / M;
    const int nblocks = (E + M - 1) / M;

    if (mode >= 1) {
        hipMemsetAsync(bins, 0, (size_t)NPAIR * 4, stream);
        prep_hist_kernel<<<NPREP + nhist, THREADS, 0, stream>>>(
            W_in, gate_W, W_out, b_in, anum, edge_index, edge_to_src,
            Wb, Gb, Ob, pairids, bins, E);
        scan_kernel<<<1, THREADS, 0, stream>>>(bins, NPAIR);
        scatter_hpre_kernel<<<nhist + npb, THREADS, 0, stream>>>(
            emb_table, Wb, pairids, dist, bins, ip, spair, sdist, hpreF,
            E, NPAIR, nhist, (mode == 2) ? 1 : 0);
        if (mode == 2) {
            pair_embed_srtA<<<nblocks, THREADS, 0, stream>>>(
                spair, sdist, hpreF, b_out, Wb, Gb, Ob, tmp, E);
            permute_out_kernel<<<(E + 255) / 256, 256, 0, stream>>>(
                ip, tmp, (float*)d_out, E);
        } else {
            pair_embed_srtB<<<nblocks, THREADS, 0, stream>>>(
                ip, spair, dist, hpreF, b_out, Wb, Gb, Ob, (float*)d_out, E);
        }
    } else {
        prep_hist_kernel<<<NPREP, THREADS, 0, stream>>>(
            W_in, gate_W, W_out, b_in, anum, edge_index, edge_to_src,
            Wb, Gb, Ob, pairids, bins, E);
        scatter_hpre_kernel<<<npb, THREADS, 0, stream>>>(
            emb_table, Wb, pairids, dist, bins, ip, spair, sdist, hpreF,
            E, NPAIR, 0, 0);
        pair_embed_unsrt<<<nblocks, THREADS, 0, stream>>>(
            anum, edge_index, edge_to_src, dist, hpreF, b_out,
            Wb, Gb, Ob, (float*)d_out, E);
    }
}